// Round 8
// baseline (203.935 us; speedup 1.0000x reference)
//
#include <hip/hip_runtime.h>
#include <stdint.h>

// VectorQuantizer: x[32,64,64,64] NCHW fp32, W[512,64] fp32.
// argmin_k ||x - w_k||^2 ; out = W[argmin] in NCHW.
//
// v8 = v7 minus the spill: no f32x16/f32x4 union (zero-literal acc init), and
// -0.5||w||^2 folded into a 5th MFMA per tile via a (nh_hi,nh_lo) bf16-pair
// A-fragment (k=0,1) against a ones B-fragment. Margin 2^-7*||x||*Wmax + 0.02
// (slack covers the ~1e-3 nh representation error). Structure: 512-thr blocks
// (8 waves x 32 tokens), 32x32x16 bf16 MFMA, codebook in LDS dim-octet-major
// (conflict-free immediate-offset ds_reads), 2-pass margin-certified argmax,
// fp64 refine for multi-candidate tokens, coalesced direct-global I/O.

typedef short short8 __attribute__((ext_vector_type(8)));
typedef float f32x4 __attribute__((ext_vector_type(4)));
typedef float f32x16 __attribute__((ext_vector_type(16)));

#define HW_ 4096

__device__ __forceinline__ unsigned short f2bf(float f) {
    unsigned u = __float_as_uint(f);
    u += 0x7fff + ((u >> 16) & 1);   // RNE to bf16
    return (unsigned short)(u >> 16);
}
__device__ __forceinline__ float bf2f(unsigned short h) {
    return __uint_as_float(((unsigned)h) << 16);
}

// Image: ushort idx(k,d) = (d>>3)*4096 + k*8 + (d&7)   [8 subblocks of 8KiB]
__global__ __launch_bounds__(64) void vq_prep(const float* __restrict__ W,
                                              unsigned short* __restrict__ Wb,
                                              unsigned* __restrict__ nh2,
                                              int* __restrict__ wmax2i) {
    const int k = blockIdx.x, l = threadIdx.x;
    float v = W[k * 64 + l];
    Wb[(l >> 3) * 4096 + k * 8 + (l & 7)] = f2bf(v);
    float s = v * v;
    #pragma unroll
    for (int off = 1; off < 64; off <<= 1) s += __shfl_xor(s, off);
    if (l == 0) {
        float nh = -0.5f * s;
        unsigned short nhh = f2bf(nh);
        unsigned short nhl = f2bf(nh - bf2f(nhh));
        nh2[k] = (unsigned)nhh | ((unsigned)nhl << 16);
        atomicMax(wmax2i, __float_as_int(s));   // s > 0: int order == float order
    }
}

__global__ __launch_bounds__(512, 2) void vq_main(const float* __restrict__ x,
                                                  const float* __restrict__ W,
                                                  const unsigned short* __restrict__ Wb,
                                                  const unsigned* __restrict__ nh2,
                                                  const int* __restrict__ wmax2i,
                                                  float* __restrict__ out) {
    __shared__ unsigned short cb[32768];   // 64 KiB codebook, dim-octet-major
    __shared__ unsigned nh2s[512];         // packed (bf16 nh_hi, bf16 nh_lo)
    __shared__ int bkArr[256];

    const int tid = threadIdx.x;
    const int bid = blockIdx.x;
    const int b = bid >> 4;                 // batch
    const int p0 = (bid & 15) << 8;         // 256-token spatial base
    const int l = tid & 63;
    const int wv = tid >> 6;                // wave 0..7
    const int col = l & 31;                 // token col in MFMA
    const int hi = l >> 5;                  // half-wave
    const int tokb = wv * 32 + col;         // token in block 0..255

    // ---- stage codebook + nh pairs (linear, conflict-free) ----
    {
        const f32x4* src = (const f32x4*)Wb;
        f32x4* dst = (f32x4*)cb;
        #pragma unroll
        for (int i = 0; i < 8; ++i) dst[tid + i * 512] = src[tid + i * 512];
        nh2s[tid] = nh2[tid];
    }

    // ---- B fragments direct from global; xsq on the fly ----
    short8 bf[4];
    float xsq = 0.f;
    const float* xb = x + (size_t)b * 262144 + p0 + tokb;
    #pragma unroll
    for (int s = 0; s < 4; ++s) {
        #pragma unroll
        for (int e = 0; e < 8; ++e) {
            float v = xb[(size_t)(s * 16 + hi * 8 + e) * HW_];
            xsq += v * v;
            bf[s][e] = (short)f2bf(v);
        }
    }
    xsq += __shfl_xor(xsq, 32);
    const float wm2 = __int_as_float(*wmax2i);
    const float margin = ldexpf(sqrtf(xsq * wm2), -7) + 0.02f;  // 2E certified
    __syncthreads();

    const char* Ab = (const char*)cb + hi * 8192 + col * 16;
    short8 bones = {};
    if (hi == 0) { bones[0] = (short)0x3F80; bones[1] = (short)0x3F80; }  // B=1 at k=0,1

    // score tile T: codes T*32 + row(reg,hi), row = (reg&3)+8*(reg>>2)+4*hi
    // nh folded in: D[row][col] += nh_hi[row]*1 + nh_lo[row]*1  (k=0,1)
    #define KT(T, ACC) do {                                                         \
        unsigned nhp = nh2s[(T) * 32 + col];                                        \
        short8 anh = {};                                                            \
        if (hi == 0) { anh[0] = (short)(nhp & 0xffffu);                             \
                       anh[1] = (short)(nhp >> 16); }                               \
        short8 a0 = *(const short8*)(Ab + (T) * 512);                               \
        short8 a1 = *(const short8*)(Ab + 16384 + (T) * 512);                       \
        short8 a2 = *(const short8*)(Ab + 32768 + (T) * 512);                       \
        short8 a3 = *(const short8*)(Ab + 49152 + (T) * 512);                       \
        ACC = __builtin_amdgcn_mfma_f32_32x32x16_bf16(anh, bones, ACC, 0, 0, 0);    \
        ACC = __builtin_amdgcn_mfma_f32_32x32x16_bf16(a0, bf[0], ACC, 0, 0, 0);     \
        ACC = __builtin_amdgcn_mfma_f32_32x32x16_bf16(a1, bf[1], ACC, 0, 0, 0);     \
        ACC = __builtin_amdgcn_mfma_f32_32x32x16_bf16(a2, bf[2], ACC, 0, 0, 0);     \
        ACC = __builtin_amdgcn_mfma_f32_32x32x16_bf16(a3, bf[3], ACC, 0, 0, 0);     \
    } while (0)

    // ---- pass 1: running max ----
    float m = -3.4e38f;
    #pragma unroll
    for (int T = 0; T < 16; ++T) {
        f32x16 acc = {};
        KT(T, acc);
        #pragma unroll
        for (int r = 0; r < 16; ++r) m = fmaxf(m, acc[r]);
    }
    m = fmaxf(m, __shfl_xor(m, 32));
    const float thr = m - margin;

    // ---- pass 2: rescan, build 256-bit candidate mask (bit = T*16 + reg) ----
    uint64_t msk[4] = {0, 0, 0, 0};
    #pragma unroll
    for (int T = 0; T < 16; ++T) {
        f32x16 acc = {};
        KT(T, acc);
        unsigned mt = 0;
        #pragma unroll
        for (int r = 0; r < 16; ++r) mt |= (acc[r] >= thr ? 1u : 0u) << r;
        msk[T >> 2] |= (uint64_t)mt << ((T & 3) * 16);
    }
    #undef KT

    const int cnt = __popcll(msk[0]) + __popcll(msk[1]) + __popcll(msk[2]) + __popcll(msk[3]);
    const int cntT = cnt + __shfl_xor(cnt, 32);

    // singleton fast path
    int klocal = 0x7fffffff;
    if (cnt == 1) {
        int idx = 0;
        #pragma unroll
        for (int w = 0; w < 4; ++w)
            if (msk[w]) idx = w * 64 + __builtin_ctzll(msk[w]);
        int reg = idx & 15, T = idx >> 4;
        klocal = T * 32 + (reg & 3) + 8 * (reg >> 2) + 4 * hi;
    }
    int kmin = min(klocal, __shfl_xor(klocal, 32));

    // multi-candidate: exact fp64 sum((x-w)^2), wave-cooperative
    double bd = 1.0e308;
    int bkm = 0x7fffffff;
    const bool multi = (cntT > 1);
    if (!multi) { msk[0] = msk[1] = msk[2] = msk[3] = 0; }
    uint64_t wmask = __ballot((msk[0] | msk[1] | msk[2] | msk[3]) != 0ull);
    while (wmask) {
        int L = __builtin_ctzll(wmask);
        wmask &= wmask - 1;
        const int hiL = L >> 5;
        const int tokL = wv * 32 + (L & 31);
        double xvd = (double)x[(size_t)b * 262144 + (size_t)l * HW_ + p0 + tokL];
        #pragma unroll
        for (int w = 0; w < 4; ++w) {
            uint64_t mm = __shfl(msk[w], L);
            while (mm) {
                int bit = __builtin_ctzll(mm); mm &= mm - 1;
                int idx = w * 64 + bit;
                int reg = idx & 15, T = idx >> 4;
                int k = T * 32 + (reg & 3) + 8 * (reg >> 2) + 4 * hiL;
                double dl = xvd - (double)W[k * 64 + l];
                double p = dl * dl;
                #pragma unroll
                for (int off = 1; off < 64; off <<= 1) p += __shfl_xor(p, off);
                if (l == L && (p < bd || (p == bd && k < bkm))) { bd = p; bkm = k; }
            }
        }
    }
    {   // lexicographic merge across the token's two lanes
        double od = __shfl_xor(bd, 32); int ok = __shfl_xor(bkm, 32);
        if (od < bd || (od == bd && ok < bkm)) { bd = od; bkm = ok; }
    }
    const int bk = multi ? bkm : kmin;

    if (hi == 0) bkArr[tokb] = bk;
    __syncthreads();

    // ---- epilogue: gather W rows (L2-hot), coalesced NCHW store ----
    {
        const int pp = tid & 255;            // token
        const int dh = tid >> 8;             // dim half 0..1
        const int kk = bkArr[pp];
        const float* wr = W + kk * 64 + dh * 32;
        float* ob = out + (size_t)b * 262144 + p0 + pp;
        #pragma unroll
        for (int j = 0; j < 8; ++j) {
            f32x4 v = *(const f32x4*)(wr + j * 4);
            ob[(size_t)(dh * 32 + j * 4 + 0) * HW_] = v[0];
            ob[(size_t)(dh * 32 + j * 4 + 1) * HW_] = v[1];
            ob[(size_t)(dh * 32 + j * 4 + 2) * HW_] = v[2];
            ob[(size_t)(dh * 32 + j * 4 + 3) * HW_] = v[3];
        }
    }
}

extern "C" void kernel_launch(void* const* d_in, const int* in_sizes, int n_in,
                              void* d_out, int out_size, void* d_ws, size_t ws_size,
                              hipStream_t stream) {
    const float* x = (const float*)d_in[0];
    const float* W = (const float*)d_in[1];
    unsigned short* Wb = (unsigned short*)d_ws;              // 64 KiB image
    unsigned* nh2 = (unsigned*)((char*)d_ws + 65536);        // 512 packed bf16 pairs
    int* wmax2i = (int*)((char*)d_ws + 65536 + 2048);        // 1 int (float bits)
    hipMemsetAsync(wmax2i, 0, 4, stream);
    vq_prep<<<512, 64, 0, stream>>>(W, Wb, nh2, wmax2i);
    vq_main<<<512, 512, 0, stream>>>(x, W, Wb, nh2, wmax2i, (float*)d_out);
}

// Round 9
// 72.477 us; speedup vs baseline: 2.8138x; 2.8138x over previous
//
#include <hip/hip_runtime.h>
#include <stdint.h>

// VectorQuantizer: x[32,64,64,64] NCHW fp32, W[512,64] fp32.
// argmin_k ||x - w_k||^2 ; out = W[argmin] in NCHW.
//
// v9 = r4's clean-codegen compute idiom (16x16x32 MFMA, f32x4 acc from nhs,
// mask scan, fp64 refine) + r6-8's clean data movement (full codebook resident
// in LDS dim-octet-major, direct-global B-frags, coalesced direct I/O).
// 512-thr blocks (8 waves x 16 tokens), 2-pass margin-certified argmax,
// margin 2^-7*||x||*Wmax + 0.02.

typedef short short8 __attribute__((ext_vector_type(8)));
typedef float f32x4 __attribute__((ext_vector_type(4)));

#define HW_ 4096

__device__ __forceinline__ unsigned short f2bf(float f) {
    unsigned u = __float_as_uint(f);
    u += 0x7fff + ((u >> 16) & 1);   // RNE to bf16
    return (unsigned short)(u >> 16);
}

// Image: ushort idx(k,d) = (d>>3)*4096 + k*8 + (d&7)   [8 octet-planes of 8KiB]
__global__ __launch_bounds__(64) void vq_prep(const float* __restrict__ W,
                                              unsigned short* __restrict__ Wb,
                                              float* __restrict__ nh,
                                              int* __restrict__ wmax2i) {
    const int k = blockIdx.x, l = threadIdx.x;
    float v = W[k * 64 + l];
    Wb[(l >> 3) * 4096 + k * 8 + (l & 7)] = f2bf(v);
    float s = v * v;
    #pragma unroll
    for (int off = 1; off < 64; off <<= 1) s += __shfl_xor(s, off);
    if (l == 0) {
        nh[k] = -0.5f * s;
        atomicMax(wmax2i, __float_as_int(s));   // s > 0: int order == float order
    }
}

__global__ __launch_bounds__(512, 2) void vq_main(const float* __restrict__ x,
                                                  const float* __restrict__ W,
                                                  const unsigned short* __restrict__ Wb,
                                                  const float* __restrict__ nh,
                                                  const int* __restrict__ wmax2i,
                                                  float* __restrict__ out) {
    __shared__ unsigned short cb[32768];   // 64 KiB codebook, dim-octet-major
    __shared__ float nhs[512];             // -0.5*||w||^2 (f32)
    __shared__ int bkArr[128];

    const int tid = threadIdx.x;
    const int bid = blockIdx.x;
    const int b = bid >> 5;                 // batch 0..31
    const int p0 = (bid & 31) << 7;         // 128-token spatial base
    const int l = tid & 63;
    const int wv = tid >> 6;                // wave 0..7
    const int g = l >> 4;                   // k-dim octet group 0..3
    const int tokw = l & 15;
    const int tok = wv * 16 + tokw;         // block token 0..127

    // ---- stage codebook + nhs (linear, conflict-free) ----
    {
        const f32x4* src = (const f32x4*)Wb;
        f32x4* dst = (f32x4*)cb;
        #pragma unroll
        for (int i = 0; i < 8; ++i) dst[tid + i * 512] = src[tid + i * 512];
        nhs[tid] = nh[tid];
    }

    // ---- B fragments direct from global; xsq on the fly ----
    short8 bf0, bf1;
    float xsq = 0.f;
    const float* xb = x + (size_t)b * 262144 + p0 + tok;
    #pragma unroll
    for (int e = 0; e < 8; ++e) {
        float v = xb[(size_t)(g * 8 + e) * HW_];
        xsq += v * v;
        bf0[e] = (short)f2bf(v);
    }
    #pragma unroll
    for (int e = 0; e < 8; ++e) {
        float v = xb[(size_t)(32 + g * 8 + e) * HW_];
        xsq += v * v;
        bf1[e] = (short)f2bf(v);
    }
    xsq += __shfl_xor(xsq, 16);
    xsq += __shfl_xor(xsq, 32);
    const float wm2 = __int_as_float(*wmax2i);
    const float margin = ldexpf(sqrtf(xsq * wm2), -7) + 0.02f;  // 2E certified
    __syncthreads();

    // A-read for tile t: code = t*16 + tokw, octets g (dims g*8..) and g+4 (+32)
    const char* Ab = (const char*)cb + g * 8192 + tokw * 16;

    // ---- pass 1: running max ----
    float m = -3.4e38f;
    #pragma unroll 1
    for (int tc = 0; tc < 4; ++tc) {
        #pragma unroll
        for (int tt = 0; tt < 8; ++tt) {
            const int t = tc * 8 + tt;
            short8 a0 = *(const short8*)(Ab + t * 256);
            short8 a1 = *(const short8*)(Ab + 32768 + t * 256);
            f32x4 acc = *(const f32x4*)(&nhs[t * 16 + g * 4]);
            acc = __builtin_amdgcn_mfma_f32_16x16x32_bf16(a0, bf0, acc, 0, 0, 0);
            acc = __builtin_amdgcn_mfma_f32_16x16x32_bf16(a1, bf1, acc, 0, 0, 0);
            m = fmaxf(m, fmaxf(fmaxf(acc[0], acc[1]), fmaxf(acc[2], acc[3])));
        }
    }
    m = fmaxf(m, __shfl_xor(m, 16));
    m = fmaxf(m, __shfl_xor(m, 32));
    const float thr = m - margin;

    // ---- pass 2: rescan, candidate masks (slot = t*4 + r, k = t*16+g*4+r) ----
    uint64_t c0m = 0, c1m = 0;
    #pragma unroll 1
    for (int tc = 0; tc < 4; ++tc) {
        uint64_t lo = 0;
        #pragma unroll
        for (int tt = 0; tt < 8; ++tt) {
            const int t = tc * 8 + tt;
            short8 a0 = *(const short8*)(Ab + t * 256);
            short8 a1 = *(const short8*)(Ab + 32768 + t * 256);
            f32x4 acc = *(const f32x4*)(&nhs[t * 16 + g * 4]);
            acc = __builtin_amdgcn_mfma_f32_16x16x32_bf16(a0, bf0, acc, 0, 0, 0);
            acc = __builtin_amdgcn_mfma_f32_16x16x32_bf16(a1, bf1, acc, 0, 0, 0);
            unsigned bits = 0;
            #pragma unroll
            for (int r = 0; r < 4; ++r) bits |= (acc[r] >= thr ? 1u : 0u) << r;
            lo |= (uint64_t)bits << (tt * 4);
        }
        if (tc == 0) c0m |= lo;
        else if (tc == 1) c0m |= lo << 32;
        else if (tc == 2) c1m |= lo;
        else c1m |= lo << 32;
    }

    const int cnt = __popcll(c0m) + __popcll(c1m);
    int cnt4 = cnt;
    cnt4 += __shfl_xor(cnt4, 16);
    cnt4 += __shfl_xor(cnt4, 32);

    // singleton fast path: the lone candidate is provably the exact argmin
    int klocal = 0x7fffffff;
    if (cnt == 1) {
        int slot = c0m ? __builtin_ctzll(c0m) : 64 + __builtin_ctzll(c1m);
        klocal = (slot >> 2) * 16 + g * 4 + (slot & 3);
    }
    int kmin = klocal;
    kmin = min(kmin, __shfl_xor(kmin, 16));
    kmin = min(kmin, __shfl_xor(kmin, 32));

    // multi-candidate: exact fp64 sum((x-w)^2), wave-cooperative
    double bd = 1.0e308;
    int bkm = 0x7fffffff;
    const bool multi = (cnt4 > 1);
    if (!multi) { c0m = 0; c1m = 0; }
    uint64_t wmask = __ballot((c0m | c1m) != 0ull);
    while (wmask) {
        int L = __builtin_ctzll(wmask);
        wmask &= wmask - 1;
        uint64_t mm0 = __shfl(c0m, L);
        uint64_t mm1 = __shfl(c1m, L);
        const int gL = L >> 4;
        const int tokL = wv * 16 + (L & 15);
        double xvd = (double)x[(size_t)(b * 64 + l) * HW_ + p0 + tokL];
        while (mm0 | mm1) {
            int k;
            if (mm0) {
                int s2 = __builtin_ctzll(mm0); mm0 &= mm0 - 1;
                k = (s2 >> 2) * 16 + gL * 4 + (s2 & 3);
            } else {
                int s2 = __builtin_ctzll(mm1); mm1 &= mm1 - 1;
                k = ((s2 >> 2) + 16) * 16 + gL * 4 + (s2 & 3);
            }
            double dl = xvd - (double)W[k * 64 + l];
            double p = dl * dl;
            #pragma unroll
            for (int off = 1; off < 64; off <<= 1) p += __shfl_xor(p, off);
            if (l == L && (p < bd || (p == bd && k < bkm))) { bd = p; bkm = k; }
        }
    }
    {   // lexicographic (dist, k) merge across the token's 4 lanes
        double od = __shfl_xor(bd, 16); int ok = __shfl_xor(bkm, 16);
        if (od < bd || (od == bd && ok < bkm)) { bd = od; bkm = ok; }
        od = __shfl_xor(bd, 32); ok = __shfl_xor(bkm, 32);
        if (od < bd || (od == bd && ok < bkm)) { bd = od; bkm = ok; }
    }
    const int bk = multi ? bkm : kmin;

    if (g == 0) bkArr[tok] = bk;
    __syncthreads();

    // ---- epilogue: gather W rows (L2-hot), coalesced NCHW store ----
    {
        const int pp = tid & 127;            // token
        const int dq = tid >> 7;             // dim quarter 0..3
        const int kk = bkArr[pp];
        const float* wr = W + kk * 64 + dq * 16;
        float* ob = out + (size_t)b * 262144 + p0 + pp;
        #pragma unroll
        for (int j = 0; j < 4; ++j) {
            f32x4 v = *(const f32x4*)(wr + j * 4);
            ob[(size_t)(dq * 16 + j * 4 + 0) * HW_] = v[0];
            ob[(size_t)(dq * 16 + j * 4 + 1) * HW_] = v[1];
            ob[(size_t)(dq * 16 + j * 4 + 2) * HW_] = v[2];
            ob[(size_t)(dq * 16 + j * 4 + 3) * HW_] = v[3];
        }
    }
}

extern "C" void kernel_launch(void* const* d_in, const int* in_sizes, int n_in,
                              void* d_out, int out_size, void* d_ws, size_t ws_size,
                              hipStream_t stream) {
    const float* x = (const float*)d_in[0];
    const float* W = (const float*)d_in[1];
    unsigned short* Wb = (unsigned short*)d_ws;              // 64 KiB image
    float* nh = (float*)((char*)d_ws + 65536);               // 512 f32
    int* wmax2i = (int*)((char*)d_ws + 65536 + 2048);        // 1 int (float bits)
    hipMemsetAsync(wmax2i, 0, 4, stream);
    vq_prep<<<512, 64, 0, stream>>>(W, Wb, nh, wmax2i);
    vq_main<<<1024, 512, 0, stream>>>(x, W, Wb, nh, wmax2i, (float*)d_out);
}

// Round 10
// 65.649 us; speedup vs baseline: 3.1064x; 1.1040x over previous
//
#include <hip/hip_runtime.h>
#include <stdint.h>

// VectorQuantizer: x[32,64,64,64] NCHW fp32, W[512,64] fp32.
// argmin_k ||x - w_k||^2 ; out = W[argmin] in NCHW.
//
// v10 = v9 at 2x occupancy: 1024-thr blocks (16 waves x 16 tokens = 256
// tokens/block, grid 512), launch_bounds(1024,8) -> <=64 VGPR (v9 measured 52),
// 2 blocks/CU = 32 waves/CU. Same proven kernel body: full codebook in LDS
// dim-octet-major (0 conflicts), direct-global B-frags, 2-pass margin-certified
// argmax (margin 2^-7*||x||*Wmax+0.02), fp64 refine, coalesced direct I/O.

typedef short short8 __attribute__((ext_vector_type(8)));
typedef float f32x4 __attribute__((ext_vector_type(4)));

#define HW_ 4096

__device__ __forceinline__ unsigned short f2bf(float f) {
    unsigned u = __float_as_uint(f);
    u += 0x7fff + ((u >> 16) & 1);   // RNE to bf16
    return (unsigned short)(u >> 16);
}

// Image: ushort idx(k,d) = (d>>3)*4096 + k*8 + (d&7)   [8 octet-planes of 8KiB]
__global__ __launch_bounds__(64) void vq_prep(const float* __restrict__ W,
                                              unsigned short* __restrict__ Wb,
                                              float* __restrict__ nh,
                                              int* __restrict__ wmax2i) {
    const int k = blockIdx.x, l = threadIdx.x;
    float v = W[k * 64 + l];
    Wb[(l >> 3) * 4096 + k * 8 + (l & 7)] = f2bf(v);
    float s = v * v;
    #pragma unroll
    for (int off = 1; off < 64; off <<= 1) s += __shfl_xor(s, off);
    if (l == 0) {
        nh[k] = -0.5f * s;
        atomicMax(wmax2i, __float_as_int(s));   // s > 0: int order == float order
    }
}

__global__ __launch_bounds__(1024, 8) void vq_main(const float* __restrict__ x,
                                                   const float* __restrict__ W,
                                                   const unsigned short* __restrict__ Wb,
                                                   const float* __restrict__ nh,
                                                   const int* __restrict__ wmax2i,
                                                   float* __restrict__ out) {
    __shared__ unsigned short cb[32768];   // 64 KiB codebook, dim-octet-major
    __shared__ float nhs[512];             // -0.5*||w||^2 (f32)
    __shared__ int bkArr[256];

    const int tid = threadIdx.x;
    const int bid = blockIdx.x;
    const int b = bid >> 4;                 // batch 0..31
    const int p0 = (bid & 15) << 8;         // 256-token spatial base
    const int l = tid & 63;
    const int wv = tid >> 6;                // wave 0..15
    const int g = l >> 4;                   // k-dim octet group 0..3
    const int tokw = l & 15;
    const int tok = wv * 16 + tokw;         // block token 0..255

    // ---- stage codebook + nhs (linear, conflict-free) ----
    {
        const f32x4* src = (const f32x4*)Wb;
        f32x4* dst = (f32x4*)cb;
        #pragma unroll
        for (int i = 0; i < 4; ++i) dst[tid + i * 1024] = src[tid + i * 1024];
        if (tid < 512) nhs[tid] = nh[tid];
    }

    // ---- B fragments direct from global; xsq on the fly ----
    short8 bf0, bf1;
    float xsq = 0.f;
    const float* xb = x + (size_t)b * 262144 + p0 + tok;
    #pragma unroll
    for (int e = 0; e < 8; ++e) {
        float v = xb[(size_t)(g * 8 + e) * HW_];
        xsq += v * v;
        bf0[e] = (short)f2bf(v);
    }
    #pragma unroll
    for (int e = 0; e < 8; ++e) {
        float v = xb[(size_t)(32 + g * 8 + e) * HW_];
        xsq += v * v;
        bf1[e] = (short)f2bf(v);
    }
    xsq += __shfl_xor(xsq, 16);
    xsq += __shfl_xor(xsq, 32);
    const float wm2 = __int_as_float(*wmax2i);
    const float margin = ldexpf(sqrtf(xsq * wm2), -7) + 0.02f;  // 2E certified
    __syncthreads();

    // A-read for tile t: code = t*16 + tokw, octets g (dims g*8..) and g+4 (+32)
    const char* Ab = (const char*)cb + g * 8192 + tokw * 16;

    // ---- pass 1: running max ----
    float m = -3.4e38f;
    #pragma unroll 1
    for (int tc = 0; tc < 4; ++tc) {
        #pragma unroll
        for (int tt = 0; tt < 8; ++tt) {
            const int t = tc * 8 + tt;
            short8 a0 = *(const short8*)(Ab + t * 256);
            short8 a1 = *(const short8*)(Ab + 32768 + t * 256);
            f32x4 acc = *(const f32x4*)(&nhs[t * 16 + g * 4]);
            acc = __builtin_amdgcn_mfma_f32_16x16x32_bf16(a0, bf0, acc, 0, 0, 0);
            acc = __builtin_amdgcn_mfma_f32_16x16x32_bf16(a1, bf1, acc, 0, 0, 0);
            m = fmaxf(m, fmaxf(fmaxf(acc[0], acc[1]), fmaxf(acc[2], acc[3])));
        }
    }
    m = fmaxf(m, __shfl_xor(m, 16));
    m = fmaxf(m, __shfl_xor(m, 32));
    const float thr = m - margin;

    // ---- pass 2: rescan, candidate masks (slot = t*4 + r, k = t*16+g*4+r) ----
    uint64_t c0m = 0, c1m = 0;
    #pragma unroll 1
    for (int tc = 0; tc < 4; ++tc) {
        uint64_t lo = 0;
        #pragma unroll
        for (int tt = 0; tt < 8; ++tt) {
            const int t = tc * 8 + tt;
            short8 a0 = *(const short8*)(Ab + t * 256);
            short8 a1 = *(const short8*)(Ab + 32768 + t * 256);
            f32x4 acc = *(const f32x4*)(&nhs[t * 16 + g * 4]);
            acc = __builtin_amdgcn_mfma_f32_16x16x32_bf16(a0, bf0, acc, 0, 0, 0);
            acc = __builtin_amdgcn_mfma_f32_16x16x32_bf16(a1, bf1, acc, 0, 0, 0);
            unsigned bits = 0;
            #pragma unroll
            for (int r = 0; r < 4; ++r) bits |= (acc[r] >= thr ? 1u : 0u) << r;
            lo |= (uint64_t)bits << (tt * 4);
        }
        if (tc == 0) c0m |= lo;
        else if (tc == 1) c0m |= lo << 32;
        else if (tc == 2) c1m |= lo;
        else c1m |= lo << 32;
    }

    const int cnt = __popcll(c0m) + __popcll(c1m);
    int cnt4 = cnt;
    cnt4 += __shfl_xor(cnt4, 16);
    cnt4 += __shfl_xor(cnt4, 32);

    // singleton fast path: the lone candidate is provably the exact argmin
    int klocal = 0x7fffffff;
    if (cnt == 1) {
        int slot = c0m ? __builtin_ctzll(c0m) : 64 + __builtin_ctzll(c1m);
        klocal = (slot >> 2) * 16 + g * 4 + (slot & 3);
    }
    int kmin = klocal;
    kmin = min(kmin, __shfl_xor(kmin, 16));
    kmin = min(kmin, __shfl_xor(kmin, 32));

    // multi-candidate: exact fp64 sum((x-w)^2), wave-cooperative
    double bd = 1.0e308;
    int bkm = 0x7fffffff;
    const bool multi = (cnt4 > 1);
    if (!multi) { c0m = 0; c1m = 0; }
    uint64_t wmask = __ballot((c0m | c1m) != 0ull);
    while (wmask) {
        int L = __builtin_ctzll(wmask);
        wmask &= wmask - 1;
        uint64_t mm0 = __shfl(c0m, L);
        uint64_t mm1 = __shfl(c1m, L);
        const int gL = L >> 4;
        const int tokL = wv * 16 + (L & 15);
        double xvd = (double)x[(size_t)(b * 64 + l) * HW_ + p0 + tokL];
        while (mm0 | mm1) {
            int k;
            if (mm0) {
                int s2 = __builtin_ctzll(mm0); mm0 &= mm0 - 1;
                k = (s2 >> 2) * 16 + gL * 4 + (s2 & 3);
            } else {
                int s2 = __builtin_ctzll(mm1); mm1 &= mm1 - 1;
                k = ((s2 >> 2) + 16) * 16 + gL * 4 + (s2 & 3);
            }
            double dl = xvd - (double)W[k * 64 + l];
            double p = dl * dl;
            #pragma unroll
            for (int off = 1; off < 64; off <<= 1) p += __shfl_xor(p, off);
            if (l == L && (p < bd || (p == bd && k < bkm))) { bd = p; bkm = k; }
        }
    }
    {   // lexicographic (dist, k) merge across the token's 4 lanes
        double od = __shfl_xor(bd, 16); int ok = __shfl_xor(bkm, 16);
        if (od < bd || (od == bd && ok < bkm)) { bd = od; bkm = ok; }
        od = __shfl_xor(bd, 32); ok = __shfl_xor(bkm, 32);
        if (od < bd || (od == bd && ok < bkm)) { bd = od; bkm = ok; }
    }
    const int bk = multi ? bkm : kmin;

    if (g == 0) bkArr[tok] = bk;
    __syncthreads();

    // ---- epilogue: gather W rows (L2-hot), coalesced NCHW store ----
    {
        const int pp = tid & 255;            // token
        const int dq = tid >> 8;             // dim quarter 0..3
        const int kk = bkArr[pp];
        const float* wr = W + kk * 64 + dq * 16;
        float* ob = out + (size_t)b * 262144 + p0 + pp;
        #pragma unroll
        for (int j = 0; j < 4; ++j) {
            f32x4 v = *(const f32x4*)(wr + j * 4);
            ob[(size_t)(dq * 16 + j * 4 + 0) * HW_] = v[0];
            ob[(size_t)(dq * 16 + j * 4 + 1) * HW_] = v[1];
            ob[(size_t)(dq * 16 + j * 4 + 2) * HW_] = v[2];
            ob[(size_t)(dq * 16 + j * 4 + 3) * HW_] = v[3];
        }
    }
}

extern "C" void kernel_launch(void* const* d_in, const int* in_sizes, int n_in,
                              void* d_out, int out_size, void* d_ws, size_t ws_size,
                              hipStream_t stream) {
    const float* x = (const float*)d_in[0];
    const float* W = (const float*)d_in[1];
    unsigned short* Wb = (unsigned short*)d_ws;              // 64 KiB image
    float* nh = (float*)((char*)d_ws + 65536);               // 512 f32
    int* wmax2i = (int*)((char*)d_ws + 65536 + 2048);        // 1 int (float bits)
    hipMemsetAsync(wmax2i, 0, 4, stream);
    vq_prep<<<512, 64, 0, stream>>>(W, Wb, nh, wmax2i);
    vq_main<<<512, 1024, 0, stream>>>(x, W, Wb, nh, wmax2i, (float*)d_out);
}